// Round 1
// baseline (642.335 us; speedup 1.0000x reference)
//
#include <hip/hip_runtime.h>
#include <math.h>

// Problem constants (validated against in_sizes at launch):
//   B=262144 rows, N=1e6, R=64, H=128.
// Outputs: logits [B,2] then loss scalar, all float32, concatenated.

#define H_DIM 128

// Precompute re = s*(1-s), s = sigmoid(clip(Wr,-6,6)) for the tiny 64x128 table.
__global__ void re_kernel(const float* __restrict__ Wr, float* __restrict__ re, int n) {
    int i = blockIdx.x * blockDim.x + threadIdx.x;
    if (i < n) {
        float v = Wr[i];
        v = fminf(6.0f, fmaxf(-6.0f, v));
        float s = 1.0f / (1.0f + __expf(-v));
        re[i] = s * (1.0f - s);
    }
}

// One row per 32-lane half-wave: 32 lanes x float4 = one 512B contiguous gather
// per table read. Block = 256 threads = 8 rows.
__global__ __launch_bounds__(256) void main_kernel(
    const int* __restrict__ x, const int* __restrict__ y,
    const int* __restrict__ r, const int* __restrict__ l,
    const float* __restrict__ Wx, const float* __restrict__ re,
    float* __restrict__ logits, float* __restrict__ partials, int B)
{
    const int group = threadIdx.x >> 5;   // 0..7
    const int lane  = threadIdx.x & 31;
    const int row   = blockIdx.x * 8 + group;

    __shared__ float sloss[8];
    float lossv = 0.0f;

    if (row < B) {
        const int xi = x[row];
        const int yi = y[row];
        const int ri = r[row];
        const int li = l[row];

        const float4 a = *(const float4*)(Wx + (size_t)xi * H_DIM + lane * 4);
        const float4 b = *(const float4*)(Wx + (size_t)yi * H_DIM + lane * 4);
        const float4 c = *(const float4*)(re + (size_t)ri * H_DIM + lane * 4);

        float d = a.x * b.x * c.x + a.y * b.y * c.y + a.z * b.z * c.z + a.w * b.w * c.w;
        // reduce across the 32 lanes of this row-group (xor masks < 32 stay in-group)
        #pragma unroll
        for (int off = 16; off > 0; off >>= 1) d += __shfl_xor(d, off, 64);

        if (lane == 0) {
            float p = 1.0f / (1.0f + __expf(-d));
            float q = 1.0f - p;
            float2 lg = make_float2(p, q);
            *(float2*)(logits + (size_t)row * 2) = lg;
            // CE over 2-class logits [p, q]: loss_i = logsumexp(p,q) - logits[l]
            float lse = __logf(__expf(p) + __expf(q));
            lossv = lse - (li == 0 ? p : q);
        }
    }
    if (lane == 0) sloss[group] = lossv;
    __syncthreads();
    if (threadIdx.x == 0) {
        float s = 0.0f;
        #pragma unroll
        for (int g = 0; g < 8; ++g) s += sloss[g];
        partials[blockIdx.x] = s;
    }
}

__global__ __launch_bounds__(256) void reduce_kernel(
    const float* __restrict__ partials, int n, float* __restrict__ out, double invB)
{
    __shared__ double sd[256];
    double acc = 0.0;
    for (int i = threadIdx.x; i < n; i += 256) acc += (double)partials[i];
    sd[threadIdx.x] = acc;
    __syncthreads();
    for (int s = 128; s > 0; s >>= 1) {
        if ((int)threadIdx.x < s) sd[threadIdx.x] += sd[threadIdx.x + s];
        __syncthreads();
    }
    if (threadIdx.x == 0) *out = (float)(sd[0] * invB);
}

extern "C" void kernel_launch(void* const* d_in, const int* in_sizes, int n_in,
                              void* d_out, int out_size, void* d_ws, size_t ws_size,
                              hipStream_t stream) {
    const int*   x  = (const int*)d_in[0];
    const int*   y  = (const int*)d_in[1];
    const int*   r  = (const int*)d_in[2];
    const int*   l  = (const int*)d_in[3];
    const float* Wx = (const float*)d_in[4];
    const float* Wr = (const float*)d_in[5];

    const int B  = in_sizes[0];
    const int RH = in_sizes[5];           // 64*128 = 8192

    float* logits   = (float*)d_out;              // [B,2]
    float* loss_out = logits + (size_t)B * 2;     // scalar at index 2B

    // ws layout: [re table: RH floats][partials: nblocks floats]
    float* re       = (float*)d_ws;
    const int nblocks = (B + 7) / 8;
    float* partials = re + RH;

    re_kernel<<<(RH + 255) / 256, 256, 0, stream>>>(Wr, re, RH);
    main_kernel<<<nblocks, 256, 0, stream>>>(x, y, r, l, Wx, re, logits, partials, B);
    reduce_kernel<<<1, 256, 0, stream>>>(partials, nblocks, loss_out, 1.0 / (double)B);
}

// Round 2
// 606.426 us; speedup vs baseline: 1.0592x; 1.0592x over previous
//
#include <hip/hip_runtime.h>
#include <math.h>

// B=262144 rows, N=1e6, R=64, H=128.
// Outputs: logits [B,2] (524288 f32) then loss scalar, concatenated in d_out.
//
// Bottleneck analysis (R1): dur_us=642 but top-5 rocprof dispatches are all
// harness fills (2 GB ws poison @ ~315us) — our kernels are each <312us.
// Controllable slice is the ~270 MB of random 512B row gathers (HBM/L3-bound,
// ideal ~30-60us). This round: fuse regularizer inline (Wr is 32 KB, cache
// hot; sigmoid' recompute is ~2us of VALU), 2 dispatches instead of 3.

#define H_DIM 128

__global__ __launch_bounds__(256) void fused_kernel(
    const int* __restrict__ x, const int* __restrict__ y,
    const int* __restrict__ r, const int* __restrict__ l,
    const float* __restrict__ Wx, const float* __restrict__ Wr,
    float* __restrict__ logits, float* __restrict__ partials,
    int ngroups)  // ngroups = B/8 row-groups of 8 rows
{
    const int group = threadIdx.x >> 5;   // 0..7 (half-wave per row)
    const int lane  = threadIdx.x & 31;

    __shared__ float sloss[8];
    float lossacc = 0.0f;

    for (int g = blockIdx.x; g < ngroups; g += gridDim.x) {
        const int row = g * 8 + group;
        // uniform across the 32-lane group -> broadcast loads
        const int xi = x[row];
        const int yi = y[row];
        const int ri = r[row];
        const int li = l[row];

        const float4 a = *(const float4*)(Wx + (size_t)xi * H_DIM + lane * 4);
        const float4 b = *(const float4*)(Wx + (size_t)yi * H_DIM + lane * 4);
        const float4 w = *(const float4*)(Wr + (size_t)ri * H_DIM + lane * 4);

        // re = s*(1-s), s = sigmoid(clamp(w, -6, 6)) — recomputed inline
        float4 c;
        {
            float v0 = fminf(6.0f, fmaxf(-6.0f, w.x));
            float v1 = fminf(6.0f, fmaxf(-6.0f, w.y));
            float v2 = fminf(6.0f, fmaxf(-6.0f, w.z));
            float v3 = fminf(6.0f, fmaxf(-6.0f, w.w));
            float s0 = 1.0f / (1.0f + __expf(-v0));
            float s1 = 1.0f / (1.0f + __expf(-v1));
            float s2 = 1.0f / (1.0f + __expf(-v2));
            float s3 = 1.0f / (1.0f + __expf(-v3));
            c.x = s0 * (1.0f - s0);
            c.y = s1 * (1.0f - s1);
            c.z = s2 * (1.0f - s2);
            c.w = s3 * (1.0f - s3);
        }

        float d = a.x * b.x * c.x + a.y * b.y * c.y
                + a.z * b.z * c.z + a.w * b.w * c.w;
        // reduce across the 32 lanes of this group (xor masks <32 stay in-group)
        #pragma unroll
        for (int off = 16; off > 0; off >>= 1) d += __shfl_xor(d, off, 64);

        if (lane == 0) {
            float p = 1.0f / (1.0f + __expf(-d));
            float q = 1.0f - p;
            *(float2*)(logits + (size_t)row * 2) = make_float2(p, q);
            // CE over 2-class logits [p,q]: loss_i = log(e^p + e^q) - chosen
            float lse = __logf(__expf(p) + __expf(q));
            lossacc += lse - (li == 0 ? p : q);
        }
    }

    if (lane == 0) sloss[group] = lossacc;
    __syncthreads();
    if (threadIdx.x == 0) {
        float s = 0.0f;
        #pragma unroll
        for (int gi = 0; gi < 8; ++gi) s += sloss[gi];
        partials[blockIdx.x] = s;
    }
}

__global__ __launch_bounds__(256) void reduce_kernel(
    const float* __restrict__ partials, int n, float* __restrict__ out, double invB)
{
    __shared__ double sd[256];
    double acc = 0.0;
    for (int i = threadIdx.x; i < n; i += 256) acc += (double)partials[i];
    sd[threadIdx.x] = acc;
    __syncthreads();
    for (int s = 128; s > 0; s >>= 1) {
        if ((int)threadIdx.x < s) sd[threadIdx.x] += sd[threadIdx.x + s];
        __syncthreads();
    }
    if (threadIdx.x == 0) *out = (float)(sd[0] * invB);
}

extern "C" void kernel_launch(void* const* d_in, const int* in_sizes, int n_in,
                              void* d_out, int out_size, void* d_ws, size_t ws_size,
                              hipStream_t stream) {
    const int*   x  = (const int*)d_in[0];
    const int*   y  = (const int*)d_in[1];
    const int*   r  = (const int*)d_in[2];
    const int*   l  = (const int*)d_in[3];
    const float* Wx = (const float*)d_in[4];
    const float* Wr = (const float*)d_in[5];

    const int B = in_sizes[0];

    float* logits   = (float*)d_out;            // [B,2]
    float* loss_out = logits + (size_t)B * 2;   // scalar

    float* partials = (float*)d_ws;             // [NBLK]
    const int ngroups = (B + 7) / 8;            // 32768
    const int NBLK = 4096;                      // 16 blocks/CU, grid-stride x8

    fused_kernel<<<NBLK, 256, 0, stream>>>(x, y, r, l, Wx, Wr, logits, partials, ngroups);
    reduce_kernel<<<1, 256, 0, stream>>>(partials, NBLK, loss_out, 1.0 / (double)B);
}